// Round 13
// baseline (107.549 us; speedup 1.0000x reference)
//
#include <hip/hip_runtime.h>
#include <math.h>

#define NN 4096
#define DD 512
#define K_TOP 10
#define K_HALF 5

typedef short bf16x8 __attribute__((ext_vector_type(8)));
typedef float f32x4 __attribute__((ext_vector_type(4)));
typedef unsigned short ushort8v __attribute__((ext_vector_type(8)));

// ---------------- helpers ----------------

__device__ inline float block_reduce_sum_f(float v, float* red) {
    int tid = threadIdx.x;
    red[tid] = v;
    __syncthreads();
    for (int st = 128; st > 0; st >>= 1) {
        if (tid < st) red[tid] += red[tid + st];
        __syncthreads();
    }
    float r = red[0];
    __syncthreads();
    return r;
}

__device__ inline double block_reduce_sum_d(double v, double* red) {
    int tid = threadIdx.x;
    red[tid] = v;
    __syncthreads();
    for (int st = 128; st > 0; st >>= 1) {
        if (tid < st) red[tid] += red[tid + st];
        __syncthreads();
    }
    double r = red[0];
    __syncthreads();
    return r;
}

__device__ inline unsigned short f2bf(float x) {
    unsigned u = __float_as_uint(x);
    unsigned r = (u + 0x7fffu + ((u >> 16) & 1u)) >> 16;
    return (unsigned short)r;
}

__device__ inline float bf2f(unsigned short b) {
    unsigned u = ((unsigned)b) << 16;
    return __uint_as_float(u);
}

__device__ inline void gload_lds16(const void* g, void* l) {
    __builtin_amdgcn_global_load_lds((const __attribute__((address_space(1))) void*)g,
                                     (__attribute__((address_space(3))) void*)l, 16, 0, 0);
}

// ---------------- K0: norms + bf16 casts (s and normalized t) ----------------

__global__ __launch_bounds__(256) void prep_kernel(
    const float* __restrict__ s, const float* __restrict__ t,
    unsigned short* __restrict__ shi, unsigned short* __restrict__ thi,
    float* __restrict__ sn2, float* __restrict__ tn2)
{
    int row = blockIdx.x;
    int tid = threadIdx.x;
    const float* srow = s + (size_t)row * DD;
    const float* trow = t + (size_t)row * DD;
    float s0 = srow[tid], s1 = srow[tid + 256];
    float t0 = trow[tid], t1 = trow[tid + 256];
    __shared__ float red[256];
    float ssum = block_reduce_sum_f(s0 * s0 + s1 * s1, red);
    float tsum = block_reduce_sum_f(t0 * t0 + t1 * t1, red);
    float nrm = fmaxf(sqrtf(tsum), 1e-12f);
    float u0 = t0 / nrm, u1 = t1 / nrm;
    float usum = block_reduce_sum_f(u0 * u0 + u1 * u1, red);
    shi[(size_t)row * DD + tid] = f2bf(s0);
    shi[(size_t)row * DD + tid + 256] = f2bf(s1);
    thi[(size_t)row * DD + tid] = f2bf(u0);
    thi[(size_t)row * DD + tid + 256] = f2bf(u1);
    if (tid == 0) {
        sn2[row] = ssum;
        tn2[row] = usum;
    }
}

// ---------------- K1: fused symmetric bf16 MFMA Gram ----------------
// Paired phases: 8 barriers/waits, 2 K-steps (32 MFMA) per phase.
// 5-slot ring of 16KB step buffers (80 KB LDS); counted s_waitcnt vmcnt(4)
// keeps 1 stage in flight across the wait (3 stages outstanding at issue time).

#define BM 128
#define BK 32
#define NSTEP (DD / BK)   // 16
#define NPHASE (NSTEP / 2) // 8

__global__ __launch_bounds__(256) void gram_fused_kernel(
    const unsigned short* __restrict__ shi, const unsigned short* __restrict__ thi,
    const float* __restrict__ sn2, const float* __restrict__ tn2,
    unsigned short* __restrict__ Sb, unsigned short* __restrict__ Wb, int ntri)
{
    __shared__ unsigned short smem[5 * 8192];  // 80 KB; epilogue reuses first 32 KB

    int nwg = gridDim.x;
    int per = nwg >> 3;
    int bid = (blockIdx.x & 7) * per + (blockIdx.x >> 3);

    bool isS = (bid < ntri);
    int q = isS ? bid : bid - ntri;
    const unsigned short* Xhi = isS ? shi : thi;
    const float* xsq = isS ? sn2 : tn2;
    unsigned short* out = isS ? Sb : Wb;

    int bi = 0;
    while (q >= (NN / BM - bi)) { q -= (NN / BM - bi); ++bi; }
    int bj = bi + q;
    int i0 = bi * BM, j0 = bj * BM;

    int t = threadIdx.x;
    int wave = t >> 6, lane = t & 63;
    int wr = wave >> 1, wc = wave & 1;

    f32x4 acc[4][4] = {};

    int srow = t >> 2;
    int slot = t & 3;
    int ksrc = slot ^ ((srow >> 1) & 3);
    int scol = ksrc * 8;

    // hoisted staging pointers
    const unsigned short* gA0 = Xhi + (size_t)(i0 + srow) * DD + scol;
    const unsigned short* gA1 = Xhi + (size_t)(i0 + 64 + srow) * DD + scol;
    const unsigned short* gB0 = Xhi + (size_t)(j0 + srow) * DD + scol;
    const unsigned short* gB1 = Xhi + (size_t)(j0 + 64 + srow) * DD + scol;
    const int ldsoff = t * 8;

    // hoisted LDS fragment byte offsets
    int fr = lane & 15, kg = lane >> 4;
    int aoff[4], boff[4];
#pragma unroll
    for (int m = 0; m < 4; ++m) {
        int row = wr * 64 + m * 16 + fr;
        aoff[m] = (row * BK + ((kg ^ ((row >> 1) & 3)) << 3)) * 2;
    }
#pragma unroll
    for (int n = 0; n < 4; ++n) {
        int row = wc * 64 + n * 16 + fr;
        boff[n] = (row * BK + ((kg ^ ((row >> 1) & 3)) << 3)) * 2 + 8192;
    }
    const char* smemc = (const char*)smem;

    auto stage = [&](int step) {
        unsigned short* base = smem + (step % 5) * 8192;
        gload_lds16(gA0 + step * BK, base + ldsoff);
        gload_lds16(gA1 + step * BK, base + 2048 + ldsoff);
        gload_lds16(gB0 + step * BK, base + 4096 + ldsoff);
        gload_lds16(gB1 + step * BK, base + 6144 + ldsoff);
    };

    stage(0);
    stage(1);
    stage(2);
#pragma unroll
    for (int p = 0; p < NPHASE; ++p) {
        // wait for steps 2p, 2p+1 (stage 2p+2 stays in flight), then barrier
        if (p < NPHASE - 1)
            asm volatile("s_waitcnt vmcnt(4)" ::: "memory");
        else
            asm volatile("s_waitcnt vmcnt(0)" ::: "memory");
        __builtin_amdgcn_s_barrier();
        // buffers (2p+3)%5 and (2p+4)%5 were consumed at phase p-1 (barrier-ordered)
        if (2 * p + 3 < NSTEP) stage(2 * p + 3);
        if (2 * p + 4 < NSTEP) stage(2 * p + 4);

#pragma unroll
        for (int h = 0; h < 2; ++h) {
            const int sub = 2 * p + h;
            const int bufb = (sub % 5) * 16384;   // compile-time per unrolled iter
            bf16x8 ah[4], bh[4];
#pragma unroll
            for (int m = 0; m < 4; ++m)
                ah[m] = *(const bf16x8*)(smemc + bufb + aoff[m]);
#pragma unroll
            for (int n = 0; n < 4; ++n)
                bh[n] = *(const bf16x8*)(smemc + bufb + boff[n]);
            __builtin_amdgcn_s_setprio(1);
#pragma unroll
            for (int m = 0; m < 4; ++m)
#pragma unroll
                for (int n = 0; n < 4; ++n)
                    acc[m][n] = __builtin_amdgcn_mfma_f32_16x16x32_bf16(ah[m], bh[n], acc[m][n], 0, 0, 0);
            __builtin_amdgcn_s_setprio(0);
        }
    }
    __syncthreads();

    // ---- epilogue: stage bf16 tile in LDS (swizzled), write vectorized ----
    int fq = lane >> 4;
    float xj[4];
#pragma unroll
    for (int n = 0; n < 4; ++n) xj[n] = xsq[j0 + wc * 64 + n * 16 + fr];
#pragma unroll
    for (int m = 0; m < 4; ++m) {
        int rbase = wr * 64 + m * 16 + fq * 4;
        float xi[4];
#pragma unroll
        for (int r = 0; r < 4; ++r) xi[r] = xsq[i0 + rbase + r];
#pragma unroll
        for (int n = 0; n < 4; ++n) {
            int col = wc * 64 + n * 16 + fr;
#pragma unroll
            for (int r = 0; r < 4; ++r) {
                int rl = rbase + r;
                float d2 = xi[r] + xj[n] - 2.0f * acc[m][n][r];
                d2 = fmaxf(d2, 0.0f);
                float v = isS ? sqrtf(d2) : expf(-d2);
                smem[rl * BM + (col ^ (((rl >> 2) & 7) << 3))] = f2bf(v);
            }
        }
    }
    __syncthreads();

    int chunk = t & 15;
#pragma unroll
    for (int p = 0; p < 8; ++p) {
        int rl = p * 16 + (t >> 4);
        int sc = (chunk * 8) ^ (((rl >> 2) & 7) << 3);
        ushort8v vv = *(const ushort8v*)&smem[rl * BM + sc];
        *(ushort8v*)&out[(size_t)(i0 + rl) * NN + j0 + chunk * 8] = vv;
    }

    if (bi != bj) {
        int sub = lane & 7;
        int g = lane >> 3;
#pragma unroll
        for (int pj = 0; pj < 4; ++pj) {
#pragma unroll
            for (int pi = 0; pi < 2; ++pi) {
                int jl = pj * 32 + wave * 8 + g;
                int ic = pi * 8 + sub;
                int ib = ic * 8;
                ushort8v vv;
#pragma unroll
                for (int k = 0; k < 8; ++k) {
                    int irow = ib + k;
                    vv[k] = smem[irow * BM + (jl ^ (((irow >> 2) & 7) << 3))];
                }
                *(ushort8v*)&out[(size_t)(j0 + jl) * NN + i0 + ib] = vv;
            }
        }
    }
}

// ---------------- K2: fused per-row pass: rowmean + dense-loss + top-10 ----------------

__global__ __launch_bounds__(256) void fused_row_kernel(
    const unsigned short* __restrict__ Sb, const unsigned short* __restrict__ Wb,
    const int* __restrict__ idx, float* __restrict__ invm,
    int* __restrict__ topk, double* __restrict__ pDense)
{
    __shared__ unsigned mk[256 * K_TOP];
    __shared__ float redf[256];
    __shared__ double redd[256];

    int row = blockIdx.x, tid = threadIdx.x;
    const ushort8v* S8 = (const ushort8v*)(Sb + (size_t)row * NN);
    const ushort8v* W8 = (const ushort8v*)(Wb + (size_t)row * NN);

    ushort8v sv[2], wv[2];
    sv[0] = S8[tid]; sv[1] = S8[tid + 256];
    wv[0] = W8[tid]; wv[1] = W8[tid + 256];

    float acc = 0.f;
#pragma unroll
    for (int q = 0; q < 2; ++q) {
        float a = 0.f;
#pragma unroll
        for (int c = 0; c < 8; ++c) a += bf2f(sv[q][c]);
        acc += a;
    }
    float total = block_reduce_sum_f(acc, redf);
    float mean = total / (float)NN;
    float im = 1.0f / mean;
    if (tid == 0) invm[row] = im;

    double dacc = 0.0;
#pragma unroll
    for (int q = 0; q < 2; ++q) {
        int j8 = tid + 256 * q;
        float part = 0.f;
        bool hasdiag = (j8 * 8 <= row) && (row < j8 * 8 + 8);
#pragma unroll
        for (int c = 0; c < 8; ++c) {
            float sc = bf2f(sv[q][c]) * im;
            float rr = fmaxf(1.0f - sc, 0.0f);
            float term = rr * rr + 0.5f * bf2f(wv[q][c]) * (sc * sc - rr * rr);
            part += term;
        }
        if (hasdiag) {
            int c = row - j8 * 8;
            float sc = bf2f(sv[q][c]) * im;
            float rr = fmaxf(1.0f - sc, 0.0f);
            part -= rr * rr + 0.5f * bf2f(wv[q][c]) * (sc * sc - rr * rr);
        }
        dacc += (double)part;
    }
    double dtot = block_reduce_sum_d(dacc, redd);
    if (tid == 0) pDense[row] = dtot;

    int myidx = idx[row];
    const int4* i4 = (const int4*)idx;
    unsigned v[K_TOP];
#pragma unroll
    for (int p = 0; p < K_TOP; ++p) v[p] = 0u;

#pragma unroll
    for (int q = 0; q < 2; ++q) {
        int j8 = tid + 256 * q;
        int4 ia = i4[j8 * 2];
        int4 ib = i4[j8 * 2 + 1];
        int ii[8] = {ia.x, ia.y, ia.z, ia.w, ib.x, ib.y, ib.z, ib.w};
#pragma unroll
        for (int c = 0; c < 8; ++c) {
            int j = j8 * 8 + c;
            unsigned val = (ii[c] == myidx) ? 0x3F80u : (unsigned)(unsigned short)wv[q][c];
            unsigned nk = (val << 16) | (unsigned)(4095 - j);
            if (nk > v[K_TOP - 1]) {
#pragma unroll
                for (int p = K_TOP - 1; p >= 1; --p) {
                    if (nk > v[p - 1]) v[p] = v[p - 1];
                    else if (nk > v[p]) v[p] = nk;
                }
                if (nk > v[0]) v[0] = nk;
            }
        }
    }

#pragma unroll
    for (int p = 0; p < K_TOP; ++p) mk[tid * K_TOP + p] = v[p];
    __syncthreads();

    for (int stride = 128; stride >= 1; stride >>= 1) {
        if (tid < stride) {
            int a = tid * K_TOP, b = (tid + stride) * K_TOP;
            unsigned ov[K_TOP];
            int pa = 0, pb = 0;
#pragma unroll
            for (int p = 0; p < K_TOP; ++p) {
                unsigned va = mk[a + pa], vb = mk[b + pb];
                bool ta = (va > vb);
                ov[p] = ta ? va : vb;
                pa += ta ? 1 : 0;
                pb += ta ? 0 : 1;
            }
#pragma unroll
            for (int p = 0; p < K_TOP; ++p) mk[a + p] = ov[p];
        }
        __syncthreads();
    }

    if (tid == 0) {
#pragma unroll
        for (int p = 0; p < K_TOP; ++p)
            topk[row * K_TOP + p] = 4095 - (int)(mk[p] & 0xFFFFu);
    }
}

// ---------------- K3: mutual-NN lists, one row per 1-wave block ----------------

__global__ __launch_bounds__(64) void mutual_kernel(
    const int* __restrict__ topk, int* __restrict__ vnbr, int* __restrict__ vcnt)
{
    int i = blockIdx.x;
    int lane = threadIdx.x;
    int j = -1;
    bool flag = false;
    if (lane < K_TOP) {
        j = topk[i * K_TOP + lane];
#pragma unroll
        for (int b = 0; b < K_TOP; ++b) flag |= (topk[j * K_TOP + b] == i);
    }
    unsigned long long mask = __ballot(flag);
    int cnt = __popcll(mask & 0x3FFull);
    if (flag) {
        int pos = __popcll(mask & ((1ull << lane) - 1ull));
        vnbr[i * K_TOP + pos] = j;
    }
    if (lane >= cnt && lane < K_TOP) vnbr[i * K_TOP + lane] = -1;
    if (lane == 0) vcnt[i] = cnt;
}

// ---------------- K4: W_C_tilda values, one row per 1-wave block ----------------

__global__ __launch_bounds__(64) void wct_kernel(
    const int* __restrict__ vnbr, const int* __restrict__ vcnt, float* __restrict__ wct)
{
    int i = blockIdx.x;
    int lane = threadIdx.x;
    __shared__ int mine[K_TOP];
    int cnt = vcnt[i];
    if (lane < K_TOP) mine[lane] = vnbr[i * K_TOP + lane];
    __syncthreads();
    if (lane < K_TOP) {
        float val = 0.0f;
        if (lane < cnt) {
            int j = mine[lane];
            int cj = vcnt[j];
            int co = 0;
            for (int b = 0; b < cj; ++b) {
                int v = vnbr[j * K_TOP + b];
#pragma unroll
                for (int c = 0; c < K_TOP; ++c)
                    co += (c < cnt && mine[c] == v) ? 1 : 0;
            }
            val = (float)co / fmaxf((float)cnt, 1.0f);
        }
        wct[i * K_TOP + lane] = val;
    }
}

// ---------------- K5: sparse W_C correction, one row per 1-wave block ----------------

__global__ __launch_bounds__(64) void corr_kernel(
    const int* __restrict__ topk, const int* __restrict__ vnbr, const int* __restrict__ vcnt,
    const float* __restrict__ wct, const unsigned short* __restrict__ Sb,
    const float* __restrict__ invm, double* __restrict__ pCorr)
{
    int r = blockIdx.x;
    int lane = threadIdx.x;
    double acc = 0.0;
    if (lane < K_HALF * K_TOP) {
        int a = lane / K_TOP, b = lane % K_TOP;
        int k = topk[r * K_TOP + a];
        if (b < vcnt[k]) {
            int c = vnbr[k * K_TOP + b];
            if (c != r) {
                float w = wct[k * K_TOP + b];
                float sr = bf2f(Sb[(size_t)r * NN + c]);
                float im_r = invm[r];
                float s1 = sr * im_r;
                float r1 = fmaxf(1.0f - s1, 0.0f);
                float g1 = s1 * s1 - r1 * r1;
                float s2 = sr * invm[c];
                float r2 = fmaxf(1.0f - s2, 0.0f);
                float g2 = s2 * s2 - r2 * r2;
                acc = (double)(w * (g1 + g2)) * (1.0 / 20.0);
            }
        }
    }
#pragma unroll
    for (int off = 32; off > 0; off >>= 1) acc += __shfl_down(acc, off);
    if (lane == 0) pCorr[r] = acc;
}

// ---------------- K6: final reduce ----------------

__global__ __launch_bounds__(256) void final_kernel(
    const double* __restrict__ pDense, const double* __restrict__ pCorr, float* __restrict__ out)
{
    int tid = threadIdx.x;
    double a = 0.0;
    for (int j = tid; j < NN; j += 256) a += pDense[j] + pCorr[j];
    __shared__ double red[256];
    double total = block_reduce_sum_d(a, red);
    if (tid == 0) out[0] = (float)(total / ((double)NN * (double)(NN - 1)));
}

// ---------------- launcher ----------------

extern "C" void kernel_launch(void* const* d_in, const int* in_sizes, int n_in,
                              void* d_out, int out_size, void* d_ws, size_t ws_size,
                              hipStream_t stream)
{
    const float* s = (const float*)d_in[0];
    const float* t = (const float*)d_in[1];
    const int* idx = (const int*)d_in[2];
    float* out = (float*)d_out;

    char* base = (char*)d_ws;
    size_t off = 0;
    auto alloc = [&](size_t bytes) -> void* {
        void* p = base + off;
        off = (off + bytes + 511) & ~(size_t)511;
        return p;
    };

    unsigned short* Sb = (unsigned short*)alloc((size_t)NN * NN * 2);
    unsigned short* Wb = (unsigned short*)alloc((size_t)NN * NN * 2);
    unsigned short* shi = (unsigned short*)alloc((size_t)NN * DD * 2);
    unsigned short* thi = (unsigned short*)alloc((size_t)NN * DD * 2);
    float* sn2  = (float*)alloc(NN * 4);
    float* tn2  = (float*)alloc(NN * 4);
    float* invm = (float*)alloc(NN * 4);
    int* topk   = (int*)alloc(NN * K_TOP * 4);
    int* vnbr   = (int*)alloc(NN * K_TOP * 4);
    int* vcnt   = (int*)alloc(NN * 4);
    float* wct  = (float*)alloc(NN * K_TOP * 4);
    double* pDense = (double*)alloc(NN * 8);
    double* pCorr  = (double*)alloc(NN * 8);
    (void)ws_size;

    int ntile = NN / BM;
    int ntri = ntile * (ntile + 1) / 2;

    prep_kernel<<<NN, 256, 0, stream>>>(s, t, shi, thi, sn2, tn2);
    gram_fused_kernel<<<2 * ntri, 256, 0, stream>>>(shi, thi, sn2, tn2, Sb, Wb, ntri);
    fused_row_kernel<<<NN, 256, 0, stream>>>(Sb, Wb, idx, invm, topk, pDense);
    mutual_kernel<<<NN, 64, 0, stream>>>(topk, vnbr, vcnt);
    wct_kernel<<<NN, 64, 0, stream>>>(vnbr, vcnt, wct);
    corr_kernel<<<NN, 64, 0, stream>>>(topk, vnbr, vcnt, wct, Sb, invm, pCorr);
    final_kernel<<<1, 256, 0, stream>>>(pDense, pCorr, out);
}

// Round 14
// 98.942 us; speedup vs baseline: 1.0870x; 1.0870x over previous
//
#include <hip/hip_runtime.h>
#include <math.h>

#define NN 4096
#define DD 512
#define K_TOP 10
#define K_HALF 5

typedef short bf16x8 __attribute__((ext_vector_type(8)));
typedef float f32x4 __attribute__((ext_vector_type(4)));
typedef unsigned short ushort8v __attribute__((ext_vector_type(8)));

// ---------------- helpers ----------------

__device__ inline float wave_reduce_f(float v) {
#pragma unroll
    for (int off = 32; off > 0; off >>= 1) v += __shfl_down(v, off);
    return v;
}

__device__ inline double wave_reduce_d(double v) {
#pragma unroll
    for (int off = 32; off > 0; off >>= 1) v += __shfl_down(v, off);
    return v;
}

__device__ inline double block_reduce_sum_d(double v, double* red) {
    int tid = threadIdx.x;
    red[tid] = v;
    __syncthreads();
    for (int st = 128; st > 0; st >>= 1) {
        if (tid < st) red[tid] += red[tid + st];
        __syncthreads();
    }
    double r = red[0];
    __syncthreads();
    return r;
}

__device__ inline unsigned short f2bf(float x) {
    unsigned u = __float_as_uint(x);
    unsigned r = (u + 0x7fffu + ((u >> 16) & 1u)) >> 16;
    return (unsigned short)r;
}

__device__ inline float bf2f(unsigned short b) {
    unsigned u = ((unsigned)b) << 16;
    return __uint_as_float(u);
}

__device__ inline void gload_lds16(const void* g, void* l) {
    __builtin_amdgcn_global_load_lds((const __attribute__((address_space(1))) void*)g,
                                     (__attribute__((address_space(3))) void*)l, 16, 0, 0);
}

// ---------------- K0: norms + bf16 casts (shfl reduces, 2 barriers) ----------------

__global__ __launch_bounds__(256) void prep_kernel(
    const float* __restrict__ s, const float* __restrict__ t,
    unsigned short* __restrict__ shi, unsigned short* __restrict__ thi,
    float* __restrict__ sn2, float* __restrict__ tn2)
{
    int row = blockIdx.x;
    int tid = threadIdx.x;
    int wid = tid >> 6, lane = tid & 63;
    __shared__ float rA[4], rB[4], rC[4];
    const float* srow = s + (size_t)row * DD;
    const float* trow = t + (size_t)row * DD;
    float s0 = srow[tid], s1 = srow[tid + 256];
    float t0 = trow[tid], t1 = trow[tid + 256];
    float sw = wave_reduce_f(s0 * s0 + s1 * s1);
    float tw = wave_reduce_f(t0 * t0 + t1 * t1);
    if (lane == 0) { rA[wid] = sw; rB[wid] = tw; }
    __syncthreads();
    float ssum = rA[0] + rA[1] + rA[2] + rA[3];
    float tsum = rB[0] + rB[1] + rB[2] + rB[3];
    float nrm = fmaxf(sqrtf(tsum), 1e-12f);
    float u0 = t0 / nrm, u1 = t1 / nrm;
    float uw = wave_reduce_f(u0 * u0 + u1 * u1);
    if (lane == 0) rC[wid] = uw;
    __syncthreads();
    float usum = rC[0] + rC[1] + rC[2] + rC[3];
    shi[(size_t)row * DD + tid] = f2bf(s0);
    shi[(size_t)row * DD + tid + 256] = f2bf(s1);
    thi[(size_t)row * DD + tid] = f2bf(u0);
    thi[(size_t)row * DD + tid + 256] = f2bf(u1);
    if (tid == 0) {
        sn2[row] = ssum;
        tn2[row] = usum;
    }
}

// ---------------- K1: fused symmetric bf16 MFMA Gram (round-12 best config) ----------------
// 3 staging buffers (16 KB each); counted s_waitcnt vmcnt(4); hoisted offsets.

#define BM 128
#define BK 32
#define NSTEP (DD / BK)

__global__ __launch_bounds__(256) void gram_fused_kernel(
    const unsigned short* __restrict__ shi, const unsigned short* __restrict__ thi,
    const float* __restrict__ sn2, const float* __restrict__ tn2,
    unsigned short* __restrict__ Sb, unsigned short* __restrict__ Wb, int ntri)
{
    __shared__ unsigned short smem[3 * 8192];  // 48 KB staging; epilogue reuses first 32 KB

    int nwg = gridDim.x;
    int per = nwg >> 3;
    int bid = (blockIdx.x & 7) * per + (blockIdx.x >> 3);

    bool isS = (bid < ntri);
    int q = isS ? bid : bid - ntri;
    const unsigned short* Xhi = isS ? shi : thi;
    const float* xsq = isS ? sn2 : tn2;
    unsigned short* out = isS ? Sb : Wb;

    int bi = 0;
    while (q >= (NN / BM - bi)) { q -= (NN / BM - bi); ++bi; }
    int bj = bi + q;
    int i0 = bi * BM, j0 = bj * BM;

    int t = threadIdx.x;
    int wave = t >> 6, lane = t & 63;
    int wr = wave >> 1, wc = wave & 1;

    f32x4 acc[4][4] = {};

    int srow = t >> 2;
    int slot = t & 3;
    int ksrc = slot ^ ((srow >> 1) & 3);
    int scol = ksrc * 8;

    const unsigned short* gA0 = Xhi + (size_t)(i0 + srow) * DD + scol;
    const unsigned short* gA1 = Xhi + (size_t)(i0 + 64 + srow) * DD + scol;
    const unsigned short* gB0 = Xhi + (size_t)(j0 + srow) * DD + scol;
    const unsigned short* gB1 = Xhi + (size_t)(j0 + 64 + srow) * DD + scol;
    const int ldsoff = t * 8;

    int fr = lane & 15, kg = lane >> 4;
    int aoff[4], boff[4];
#pragma unroll
    for (int m = 0; m < 4; ++m) {
        int row = wr * 64 + m * 16 + fr;
        aoff[m] = (row * BK + ((kg ^ ((row >> 1) & 3)) << 3)) * 2;
    }
#pragma unroll
    for (int n = 0; n < 4; ++n) {
        int row = wc * 64 + n * 16 + fr;
        boff[n] = (row * BK + ((kg ^ ((row >> 1) & 3)) << 3)) * 2 + 8192;
    }
    const char* smemc = (const char*)smem;

    auto stage = [&](int step, int kb) {
        unsigned short* base = smem + kb * 8192;
        gload_lds16(gA0 + step * BK, base + ldsoff);
        gload_lds16(gA1 + step * BK, base + 2048 + ldsoff);
        gload_lds16(gB0 + step * BK, base + 4096 + ldsoff);
        gload_lds16(gB1 + step * BK, base + 6144 + ldsoff);
    };

    stage(0, 0);
    stage(1, 1);
#pragma unroll
    for (int k = 0; k < NSTEP; ++k) {
        if (k < NSTEP - 1)
            asm volatile("s_waitcnt vmcnt(4)" ::: "memory");
        else
            asm volatile("s_waitcnt vmcnt(0)" ::: "memory");
        __builtin_amdgcn_s_barrier();
        if (k + 2 < NSTEP) stage(k + 2, (k + 2) % 3);

        const int bufb = (k % 3) * 16384;
        bf16x8 ah[4], bh[4];
#pragma unroll
        for (int m = 0; m < 4; ++m)
            ah[m] = *(const bf16x8*)(smemc + bufb + aoff[m]);
#pragma unroll
        for (int n = 0; n < 4; ++n)
            bh[n] = *(const bf16x8*)(smemc + bufb + boff[n]);
#pragma unroll
        for (int m = 0; m < 4; ++m)
#pragma unroll
            for (int n = 0; n < 4; ++n)
                acc[m][n] = __builtin_amdgcn_mfma_f32_16x16x32_bf16(ah[m], bh[n], acc[m][n], 0, 0, 0);
    }
    __syncthreads();

    // ---- epilogue: stage bf16 tile in LDS (swizzled), write vectorized ----
    int fq = lane >> 4;
    float xj[4];
#pragma unroll
    for (int n = 0; n < 4; ++n) xj[n] = xsq[j0 + wc * 64 + n * 16 + fr];
#pragma unroll
    for (int m = 0; m < 4; ++m) {
        int rbase = wr * 64 + m * 16 + fq * 4;
        float xi[4];
#pragma unroll
        for (int r = 0; r < 4; ++r) xi[r] = xsq[i0 + rbase + r];
#pragma unroll
        for (int n = 0; n < 4; ++n) {
            int col = wc * 64 + n * 16 + fr;
#pragma unroll
            for (int r = 0; r < 4; ++r) {
                int rl = rbase + r;
                float d2 = xi[r] + xj[n] - 2.0f * acc[m][n][r];
                d2 = fmaxf(d2, 0.0f);
                float v = isS ? sqrtf(d2) : expf(-d2);
                smem[rl * BM + (col ^ (((rl >> 2) & 7) << 3))] = f2bf(v);
            }
        }
    }
    __syncthreads();

    int chunk = t & 15;
#pragma unroll
    for (int p = 0; p < 8; ++p) {
        int rl = p * 16 + (t >> 4);
        int sc = (chunk * 8) ^ (((rl >> 2) & 7) << 3);
        ushort8v vv = *(const ushort8v*)&smem[rl * BM + sc];
        *(ushort8v*)&out[(size_t)(i0 + rl) * NN + j0 + chunk * 8] = vv;
    }

    if (bi != bj) {
        int sub = lane & 7;
        int g = lane >> 3;
#pragma unroll
        for (int pj = 0; pj < 4; ++pj) {
#pragma unroll
            for (int pi = 0; pi < 2; ++pi) {
                int jl = pj * 32 + wave * 8 + g;
                int ic = pi * 8 + sub;
                int ib = ic * 8;
                ushort8v vv;
#pragma unroll
                for (int k = 0; k < 8; ++k) {
                    int irow = ib + k;
                    vv[k] = smem[irow * BM + (jl ^ (((irow >> 2) & 7) << 3))];
                }
                *(ushort8v*)&out[(size_t)(j0 + jl) * NN + i0 + ib] = vv;
            }
        }
    }
}

// ---------------- K2: fused per-row pass (shfl reduces + low-barrier merge) ----------------

__global__ __launch_bounds__(256) void fused_row_kernel(
    const unsigned short* __restrict__ Sb, const unsigned short* __restrict__ Wb,
    const int* __restrict__ idx, float* __restrict__ invm,
    int* __restrict__ topk, double* __restrict__ pDense)
{
    __shared__ unsigned mk[256 * K_TOP];
    __shared__ float rF[4];
    __shared__ double rD[4];

    int row = blockIdx.x, tid = threadIdx.x;
    int wid = tid >> 6, lane = tid & 63;
    const ushort8v* S8 = (const ushort8v*)(Sb + (size_t)row * NN);
    const ushort8v* W8 = (const ushort8v*)(Wb + (size_t)row * NN);

    ushort8v sv[2], wv[2];
    sv[0] = S8[tid]; sv[1] = S8[tid + 256];
    wv[0] = W8[tid]; wv[1] = W8[tid + 256];

    // --- rowmean of Sb (1 barrier) ---
    float acc = 0.f;
#pragma unroll
    for (int q = 0; q < 2; ++q) {
        float a = 0.f;
#pragma unroll
        for (int c = 0; c < 8; ++c) a += bf2f(sv[q][c]);
        acc += a;
    }
    float accw = wave_reduce_f(acc);
    if (lane == 0) rF[wid] = accw;
    __syncthreads();
    float total = rF[0] + rF[1] + rF[2] + rF[3];
    float mean = total / (float)NN;
    float im = 1.0f / mean;
    if (tid == 0) invm[row] = im;

    // --- dense loss partial (1 barrier) ---
    double dacc = 0.0;
#pragma unroll
    for (int q = 0; q < 2; ++q) {
        int j8 = tid + 256 * q;
        float part = 0.f;
        bool hasdiag = (j8 * 8 <= row) && (row < j8 * 8 + 8);
#pragma unroll
        for (int c = 0; c < 8; ++c) {
            float sc = bf2f(sv[q][c]) * im;
            float rr = fmaxf(1.0f - sc, 0.0f);
            float term = rr * rr + 0.5f * bf2f(wv[q][c]) * (sc * sc - rr * rr);
            part += term;
        }
        if (hasdiag) {
            int c = row - j8 * 8;
            float sc = bf2f(sv[q][c]) * im;
            float rr = fmaxf(1.0f - sc, 0.0f);
            part -= rr * rr + 0.5f * bf2f(wv[q][c]) * (sc * sc - rr * rr);
        }
        dacc += (double)part;
    }
    double daccw = wave_reduce_d(dacc);
    if (lane == 0) rD[wid] = daccw;
    __syncthreads();
    if (tid == 0) pDense[row] = rD[0] + rD[1] + rD[2] + rD[3];

    // --- stable top-10 via packed u32 keys ---
    int myidx = idx[row];
    const int4* i4 = (const int4*)idx;
    unsigned v[K_TOP];
#pragma unroll
    for (int p = 0; p < K_TOP; ++p) v[p] = 0u;

#pragma unroll
    for (int q = 0; q < 2; ++q) {
        int j8 = tid + 256 * q;
        int4 ia = i4[j8 * 2];
        int4 ib = i4[j8 * 2 + 1];
        int ii[8] = {ia.x, ia.y, ia.z, ia.w, ib.x, ib.y, ib.z, ib.w};
#pragma unroll
        for (int c = 0; c < 8; ++c) {
            int j = j8 * 8 + c;
            unsigned val = (ii[c] == myidx) ? 0x3F80u : (unsigned)(unsigned short)wv[q][c];
            unsigned nk = (val << 16) | (unsigned)(4095 - j);
            if (nk > v[K_TOP - 1]) {
#pragma unroll
                for (int p = K_TOP - 1; p >= 1; --p) {
                    if (nk > v[p - 1]) v[p] = v[p - 1];
                    else if (nk > v[p]) v[p] = nk;
                }
                if (nk > v[0]) v[0] = nk;
            }
        }
    }

#pragma unroll
    for (int p = 0; p < K_TOP; ++p) mk[tid * K_TOP + p] = v[p];
    __syncthreads();

    auto merge2 = [&](int aa, int bb) {
        int a = aa * K_TOP, b = bb * K_TOP;
        unsigned ov[K_TOP];
        int pa = 0, pb = 0;
#pragma unroll
        for (int p = 0; p < K_TOP; ++p) {
            unsigned va = mk[a + pa], vb = mk[b + pb];
            bool ta = (va > vb);
            ov[p] = ta ? va : vb;
            pa += ta ? 1 : 0;
            pb += ta ? 0 : 1;
        }
#pragma unroll
        for (int p = 0; p < K_TOP; ++p) mk[a + p] = ov[p];
    };

    // stride 128 (crosses waves): barrier-bracketed
    if (tid < 128) merge2(tid, tid + 128);
    __syncthreads();
    // strides <= 64 live entirely in wave 0: per-wave DS ordering, no block barriers
    if (tid < 64) {
        merge2(tid, tid + 64);
        __builtin_amdgcn_wave_barrier();
        if (tid < 32) merge2(tid, tid + 32);
        __builtin_amdgcn_wave_barrier();
        if (tid < 16) merge2(tid, tid + 16);
        __builtin_amdgcn_wave_barrier();
        if (tid < 8) merge2(tid, tid + 8);
        __builtin_amdgcn_wave_barrier();
        if (tid < 4) merge2(tid, tid + 4);
        __builtin_amdgcn_wave_barrier();
        if (tid < 2) merge2(tid, tid + 2);
        __builtin_amdgcn_wave_barrier();
        if (tid < 1) merge2(0, 1);
        if (tid == 0) {
#pragma unroll
            for (int p = 0; p < K_TOP; ++p)
                topk[row * K_TOP + p] = 4095 - (int)(mk[p] & 0xFFFFu);
        }
    }
}

// ---------------- K3: mutual-NN lists, one row per 1-wave block ----------------

__global__ __launch_bounds__(64) void mutual_kernel(
    const int* __restrict__ topk, int* __restrict__ vnbr, int* __restrict__ vcnt)
{
    int i = blockIdx.x;
    int lane = threadIdx.x;
    int j = -1;
    bool flag = false;
    if (lane < K_TOP) {
        j = topk[i * K_TOP + lane];
#pragma unroll
        for (int b = 0; b < K_TOP; ++b) flag |= (topk[j * K_TOP + b] == i);
    }
    unsigned long long mask = __ballot(flag);
    int cnt = __popcll(mask & 0x3FFull);
    if (flag) {
        int pos = __popcll(mask & ((1ull << lane) - 1ull));
        vnbr[i * K_TOP + pos] = j;
    }
    if (lane >= cnt && lane < K_TOP) vnbr[i * K_TOP + lane] = -1;
    if (lane == 0) vcnt[i] = cnt;
}

// ---------------- K4: W_C_tilda values, one row per 1-wave block ----------------

__global__ __launch_bounds__(64) void wct_kernel(
    const int* __restrict__ vnbr, const int* __restrict__ vcnt, float* __restrict__ wct)
{
    int i = blockIdx.x;
    int lane = threadIdx.x;
    __shared__ int mine[K_TOP];
    int cnt = vcnt[i];
    if (lane < K_TOP) mine[lane] = vnbr[i * K_TOP + lane];
    __syncthreads();
    if (lane < K_TOP) {
        float val = 0.0f;
        if (lane < cnt) {
            int j = mine[lane];
            int cj = vcnt[j];
            int co = 0;
            for (int b = 0; b < cj; ++b) {
                int v = vnbr[j * K_TOP + b];
#pragma unroll
                for (int c = 0; c < K_TOP; ++c)
                    co += (c < cnt && mine[c] == v) ? 1 : 0;
            }
            val = (float)co / fmaxf((float)cnt, 1.0f);
        }
        wct[i * K_TOP + lane] = val;
    }
}

// ---------------- K5: sparse W_C correction, one row per 1-wave block ----------------

__global__ __launch_bounds__(64) void corr_kernel(
    const int* __restrict__ topk, const int* __restrict__ vnbr, const int* __restrict__ vcnt,
    const float* __restrict__ wct, const unsigned short* __restrict__ Sb,
    const float* __restrict__ invm, double* __restrict__ pCorr)
{
    int r = blockIdx.x;
    int lane = threadIdx.x;
    double acc = 0.0;
    if (lane < K_HALF * K_TOP) {
        int a = lane / K_TOP, b = lane % K_TOP;
        int k = topk[r * K_TOP + a];
        if (b < vcnt[k]) {
            int c = vnbr[k * K_TOP + b];
            if (c != r) {
                float w = wct[k * K_TOP + b];
                float sr = bf2f(Sb[(size_t)r * NN + c]);
                float im_r = invm[r];
                float s1 = sr * im_r;
                float r1 = fmaxf(1.0f - s1, 0.0f);
                float g1 = s1 * s1 - r1 * r1;
                float s2 = sr * invm[c];
                float r2 = fmaxf(1.0f - s2, 0.0f);
                float g2 = s2 * s2 - r2 * r2;
                acc = (double)(w * (g1 + g2)) * (1.0 / 20.0);
            }
        }
    }
#pragma unroll
    for (int off = 32; off > 0; off >>= 1) acc += __shfl_down(acc, off);
    if (lane == 0) pCorr[r] = acc;
}

// ---------------- K6: final reduce ----------------

__global__ __launch_bounds__(256) void final_kernel(
    const double* __restrict__ pDense, const double* __restrict__ pCorr, float* __restrict__ out)
{
    int tid = threadIdx.x;
    double a = 0.0;
    for (int j = tid; j < NN; j += 256) a += pDense[j] + pCorr[j];
    __shared__ double red[256];
    double total = block_reduce_sum_d(a, red);
    if (tid == 0) out[0] = (float)(total / ((double)NN * (double)(NN - 1)));
}

// ---------------- launcher ----------------

extern "C" void kernel_launch(void* const* d_in, const int* in_sizes, int n_in,
                              void* d_out, int out_size, void* d_ws, size_t ws_size,
                              hipStream_t stream)
{
    const float* s = (const float*)d_in[0];
    const float* t = (const float*)d_in[1];
    const int* idx = (const int*)d_in[2];
    float* out = (float*)d_out;

    char* base = (char*)d_ws;
    size_t off = 0;
    auto alloc = [&](size_t bytes) -> void* {
        void* p = base + off;
        off = (off + bytes + 511) & ~(size_t)511;
        return p;
    };

    unsigned short* Sb = (unsigned short*)alloc((size_t)NN * NN * 2);
    unsigned short* Wb = (unsigned short*)alloc((size_t)NN * NN * 2);
    unsigned short* shi = (unsigned short*)alloc((size_t)NN * DD * 2);
    unsigned short* thi = (unsigned short*)alloc((size_t)NN * DD * 2);
    float* sn2  = (float*)alloc(NN * 4);
    float* tn2  = (float*)alloc(NN * 4);
    float* invm = (float*)alloc(NN * 4);
    int* topk   = (int*)alloc(NN * K_TOP * 4);
    int* vnbr   = (int*)alloc(NN * K_TOP * 4);
    int* vcnt   = (int*)alloc(NN * 4);
    float* wct  = (float*)alloc(NN * K_TOP * 4);
    double* pDense = (double*)alloc(NN * 8);
    double* pCorr  = (double*)alloc(NN * 8);
    (void)ws_size;

    int ntile = NN / BM;
    int ntri = ntile * (ntile + 1) / 2;

    prep_kernel<<<NN, 256, 0, stream>>>(s, t, shi, thi, sn2, tn2);
    gram_fused_kernel<<<2 * ntri, 256, 0, stream>>>(shi, thi, sn2, tn2, Sb, Wb, ntri);
    fused_row_kernel<<<NN, 256, 0, stream>>>(Sb, Wb, idx, invm, topk, pDense);
    mutual_kernel<<<NN, 64, 0, stream>>>(topk, vnbr, vcnt);
    wct_kernel<<<NN, 64, 0, stream>>>(vnbr, vcnt, wct);
    corr_kernel<<<NN, 64, 0, stream>>>(topk, vnbr, vcnt, wct, Sb, invm, pCorr);
    final_kernel<<<1, 256, 0, stream>>>(pDense, pCorr, out);
}

// Round 15
// 98.555 us; speedup vs baseline: 1.0913x; 1.0039x over previous
//
#include <hip/hip_runtime.h>
#include <math.h>

#define NN 4096
#define DD 512
#define K_TOP 10
#define K_HALF 5

typedef short bf16x8 __attribute__((ext_vector_type(8)));
typedef float f32x4 __attribute__((ext_vector_type(4)));
typedef unsigned short ushort8v __attribute__((ext_vector_type(8)));

// ---------------- helpers ----------------

__device__ inline float wave_reduce_f(float v) {
#pragma unroll
    for (int off = 32; off > 0; off >>= 1) v += __shfl_down(v, off);
    return v;
}

__device__ inline double wave_reduce_d(double v) {
#pragma unroll
    for (int off = 32; off > 0; off >>= 1) v += __shfl_down(v, off);
    return v;
}

__device__ inline double block_reduce_sum_d(double v, double* red) {
    int tid = threadIdx.x;
    red[tid] = v;
    __syncthreads();
    for (int st = 128; st > 0; st >>= 1) {
        if (tid < st) red[tid] += red[tid + st];
        __syncthreads();
    }
    double r = red[0];
    __syncthreads();
    return r;
}

__device__ inline unsigned short f2bf(float x) {
    unsigned u = __float_as_uint(x);
    unsigned r = (u + 0x7fffu + ((u >> 16) & 1u)) >> 16;
    return (unsigned short)r;
}

__device__ inline float bf2f(unsigned short b) {
    unsigned u = ((unsigned)b) << 16;
    return __uint_as_float(u);
}

__device__ inline void gload_lds16(const void* g, void* l) {
    __builtin_amdgcn_global_load_lds((const __attribute__((address_space(1))) void*)g,
                                     (__attribute__((address_space(3))) void*)l, 16, 0, 0);
}

// ---------------- K0: norms + bf16 casts (shfl reduces, 2 barriers) ----------------

__global__ __launch_bounds__(256) void prep_kernel(
    const float* __restrict__ s, const float* __restrict__ t,
    unsigned short* __restrict__ shi, unsigned short* __restrict__ thi,
    float* __restrict__ sn2, float* __restrict__ tn2)
{
    int row = blockIdx.x;
    int tid = threadIdx.x;
    int wid = tid >> 6, lane = tid & 63;
    __shared__ float rA[4], rB[4], rC[4];
    const float* srow = s + (size_t)row * DD;
    const float* trow = t + (size_t)row * DD;
    float s0 = srow[tid], s1 = srow[tid + 256];
    float t0 = trow[tid], t1 = trow[tid + 256];
    float sw = wave_reduce_f(s0 * s0 + s1 * s1);
    float tw = wave_reduce_f(t0 * t0 + t1 * t1);
    if (lane == 0) { rA[wid] = sw; rB[wid] = tw; }
    __syncthreads();
    float ssum = rA[0] + rA[1] + rA[2] + rA[3];
    float tsum = rB[0] + rB[1] + rB[2] + rB[3];
    float nrm = fmaxf(sqrtf(tsum), 1e-12f);
    float u0 = t0 / nrm, u1 = t1 / nrm;
    float uw = wave_reduce_f(u0 * u0 + u1 * u1);
    if (lane == 0) rC[wid] = uw;
    __syncthreads();
    float usum = rC[0] + rC[1] + rC[2] + rC[3];
    shi[(size_t)row * DD + tid] = f2bf(s0);
    shi[(size_t)row * DD + tid + 256] = f2bf(s1);
    thi[(size_t)row * DD + tid] = f2bf(u0);
    thi[(size_t)row * DD + tid + 256] = f2bf(u1);
    if (tid == 0) {
        sn2[row] = ssum;
        tn2[row] = usum;
    }
}

// ---------------- K1: fused symmetric bf16 MFMA Gram ----------------
// Round-12 best schedule + __launch_bounds__(256,4): cap regs at 128/thread
// so a 4th block becomes resident per CU (occupancy was register-capped at 3).

#define BM 128
#define BK 32
#define NSTEP (DD / BK)

__global__ __launch_bounds__(256, 4) void gram_fused_kernel(
    const unsigned short* __restrict__ shi, const unsigned short* __restrict__ thi,
    const float* __restrict__ sn2, const float* __restrict__ tn2,
    unsigned short* __restrict__ Sb, unsigned short* __restrict__ Wb, int ntri)
{
    __shared__ unsigned short smem[3 * 8192];  // 48 KB staging; epilogue reuses first 32 KB

    int nwg = gridDim.x;
    int per = nwg >> 3;
    int bid = (blockIdx.x & 7) * per + (blockIdx.x >> 3);

    bool isS = (bid < ntri);
    int q = isS ? bid : bid - ntri;
    const unsigned short* Xhi = isS ? shi : thi;
    const float* xsq = isS ? sn2 : tn2;
    unsigned short* out = isS ? Sb : Wb;

    int bi = 0;
    while (q >= (NN / BM - bi)) { q -= (NN / BM - bi); ++bi; }
    int bj = bi + q;
    int i0 = bi * BM, j0 = bj * BM;

    int t = threadIdx.x;
    int wave = t >> 6, lane = t & 63;
    int wr = wave >> 1, wc = wave & 1;

    f32x4 acc[4][4] = {};

    int srow = t >> 2;
    int slot = t & 3;
    int ksrc = slot ^ ((srow >> 1) & 3);
    int scol = ksrc * 8;

    const unsigned short* gA0 = Xhi + (size_t)(i0 + srow) * DD + scol;
    const unsigned short* gA1 = Xhi + (size_t)(i0 + 64 + srow) * DD + scol;
    const unsigned short* gB0 = Xhi + (size_t)(j0 + srow) * DD + scol;
    const unsigned short* gB1 = Xhi + (size_t)(j0 + 64 + srow) * DD + scol;
    const int ldsoff = t * 8;

    int fr = lane & 15, kg = lane >> 4;
    int aoff[4], boff[4];
#pragma unroll
    for (int m = 0; m < 4; ++m) {
        int row = wr * 64 + m * 16 + fr;
        aoff[m] = (row * BK + ((kg ^ ((row >> 1) & 3)) << 3)) * 2;
    }
#pragma unroll
    for (int n = 0; n < 4; ++n) {
        int row = wc * 64 + n * 16 + fr;
        boff[n] = (row * BK + ((kg ^ ((row >> 1) & 3)) << 3)) * 2 + 8192;
    }
    const char* smemc = (const char*)smem;

    auto stage = [&](int step, int kb) {
        unsigned short* base = smem + kb * 8192;
        gload_lds16(gA0 + step * BK, base + ldsoff);
        gload_lds16(gA1 + step * BK, base + 2048 + ldsoff);
        gload_lds16(gB0 + step * BK, base + 4096 + ldsoff);
        gload_lds16(gB1 + step * BK, base + 6144 + ldsoff);
    };

    stage(0, 0);
    stage(1, 1);
#pragma unroll
    for (int k = 0; k < NSTEP; ++k) {
        if (k < NSTEP - 1)
            asm volatile("s_waitcnt vmcnt(4)" ::: "memory");
        else
            asm volatile("s_waitcnt vmcnt(0)" ::: "memory");
        __builtin_amdgcn_s_barrier();
        if (k + 2 < NSTEP) stage(k + 2, (k + 2) % 3);

        const int bufb = (k % 3) * 16384;
        bf16x8 ah[4], bh[4];
#pragma unroll
        for (int m = 0; m < 4; ++m)
            ah[m] = *(const bf16x8*)(smemc + bufb + aoff[m]);
#pragma unroll
        for (int n = 0; n < 4; ++n)
            bh[n] = *(const bf16x8*)(smemc + bufb + boff[n]);
#pragma unroll
        for (int m = 0; m < 4; ++m)
#pragma unroll
            for (int n = 0; n < 4; ++n)
                acc[m][n] = __builtin_amdgcn_mfma_f32_16x16x32_bf16(ah[m], bh[n], acc[m][n], 0, 0, 0);
    }
    __syncthreads();

    // ---- epilogue: stage bf16 tile in LDS (swizzled), write vectorized ----
    int fq = lane >> 4;
    float xj[4];
#pragma unroll
    for (int n = 0; n < 4; ++n) xj[n] = xsq[j0 + wc * 64 + n * 16 + fr];
#pragma unroll
    for (int m = 0; m < 4; ++m) {
        int rbase = wr * 64 + m * 16 + fq * 4;
        float xi[4];
#pragma unroll
        for (int r = 0; r < 4; ++r) xi[r] = xsq[i0 + rbase + r];
#pragma unroll
        for (int n = 0; n < 4; ++n) {
            int col = wc * 64 + n * 16 + fr;
#pragma unroll
            for (int r = 0; r < 4; ++r) {
                int rl = rbase + r;
                float d2 = xi[r] + xj[n] - 2.0f * acc[m][n][r];
                d2 = fmaxf(d2, 0.0f);
                float v = isS ? sqrtf(d2) : expf(-d2);
                smem[rl * BM + (col ^ (((rl >> 2) & 7) << 3))] = f2bf(v);
            }
        }
    }
    __syncthreads();

    int chunk = t & 15;
#pragma unroll
    for (int p = 0; p < 8; ++p) {
        int rl = p * 16 + (t >> 4);
        int sc = (chunk * 8) ^ (((rl >> 2) & 7) << 3);
        ushort8v vv = *(const ushort8v*)&smem[rl * BM + sc];
        *(ushort8v*)&out[(size_t)(i0 + rl) * NN + j0 + chunk * 8] = vv;
    }

    if (bi != bj) {
        int sub = lane & 7;
        int g = lane >> 3;
#pragma unroll
        for (int pj = 0; pj < 4; ++pj) {
#pragma unroll
            for (int pi = 0; pi < 2; ++pi) {
                int jl = pj * 32 + wave * 8 + g;
                int ic = pi * 8 + sub;
                int ib = ic * 8;
                ushort8v vv;
#pragma unroll
                for (int k = 0; k < 8; ++k) {
                    int irow = ib + k;
                    vv[k] = smem[irow * BM + (jl ^ (((irow >> 2) & 7) << 3))];
                }
                *(ushort8v*)&out[(size_t)(j0 + jl) * NN + i0 + ib] = vv;
            }
        }
    }
}

// ---------------- K2: fused per-row pass (shfl reduces + low-barrier merge) ----------------

__global__ __launch_bounds__(256) void fused_row_kernel(
    const unsigned short* __restrict__ Sb, const unsigned short* __restrict__ Wb,
    const int* __restrict__ idx, float* __restrict__ invm,
    int* __restrict__ topk, double* __restrict__ pDense)
{
    __shared__ unsigned mk[256 * K_TOP];
    __shared__ float rF[4];
    __shared__ double rD[4];

    int row = blockIdx.x, tid = threadIdx.x;
    int wid = tid >> 6, lane = tid & 63;
    const ushort8v* S8 = (const ushort8v*)(Sb + (size_t)row * NN);
    const ushort8v* W8 = (const ushort8v*)(Wb + (size_t)row * NN);

    ushort8v sv[2], wv[2];
    sv[0] = S8[tid]; sv[1] = S8[tid + 256];
    wv[0] = W8[tid]; wv[1] = W8[tid + 256];

    // --- rowmean of Sb (1 barrier) ---
    float acc = 0.f;
#pragma unroll
    for (int q = 0; q < 2; ++q) {
        float a = 0.f;
#pragma unroll
        for (int c = 0; c < 8; ++c) a += bf2f(sv[q][c]);
        acc += a;
    }
    float accw = wave_reduce_f(acc);
    if (lane == 0) rF[wid] = accw;
    __syncthreads();
    float total = rF[0] + rF[1] + rF[2] + rF[3];
    float mean = total / (float)NN;
    float im = 1.0f / mean;
    if (tid == 0) invm[row] = im;

    // --- dense loss partial (1 barrier) ---
    double dacc = 0.0;
#pragma unroll
    for (int q = 0; q < 2; ++q) {
        int j8 = tid + 256 * q;
        float part = 0.f;
        bool hasdiag = (j8 * 8 <= row) && (row < j8 * 8 + 8);
#pragma unroll
        for (int c = 0; c < 8; ++c) {
            float sc = bf2f(sv[q][c]) * im;
            float rr = fmaxf(1.0f - sc, 0.0f);
            float term = rr * rr + 0.5f * bf2f(wv[q][c]) * (sc * sc - rr * rr);
            part += term;
        }
        if (hasdiag) {
            int c = row - j8 * 8;
            float sc = bf2f(sv[q][c]) * im;
            float rr = fmaxf(1.0f - sc, 0.0f);
            part -= rr * rr + 0.5f * bf2f(wv[q][c]) * (sc * sc - rr * rr);
        }
        dacc += (double)part;
    }
    double daccw = wave_reduce_d(dacc);
    if (lane == 0) rD[wid] = daccw;
    __syncthreads();
    if (tid == 0) pDense[row] = rD[0] + rD[1] + rD[2] + rD[3];

    // --- stable top-10 via packed u32 keys ---
    int myidx = idx[row];
    const int4* i4 = (const int4*)idx;
    unsigned v[K_TOP];
#pragma unroll
    for (int p = 0; p < K_TOP; ++p) v[p] = 0u;

#pragma unroll
    for (int q = 0; q < 2; ++q) {
        int j8 = tid + 256 * q;
        int4 ia = i4[j8 * 2];
        int4 ib = i4[j8 * 2 + 1];
        int ii[8] = {ia.x, ia.y, ia.z, ia.w, ib.x, ib.y, ib.z, ib.w};
#pragma unroll
        for (int c = 0; c < 8; ++c) {
            int j = j8 * 8 + c;
            unsigned val = (ii[c] == myidx) ? 0x3F80u : (unsigned)(unsigned short)wv[q][c];
            unsigned nk = (val << 16) | (unsigned)(4095 - j);
            if (nk > v[K_TOP - 1]) {
#pragma unroll
                for (int p = K_TOP - 1; p >= 1; --p) {
                    if (nk > v[p - 1]) v[p] = v[p - 1];
                    else if (nk > v[p]) v[p] = nk;
                }
                if (nk > v[0]) v[0] = nk;
            }
        }
    }

#pragma unroll
    for (int p = 0; p < K_TOP; ++p) mk[tid * K_TOP + p] = v[p];
    __syncthreads();

    auto merge2 = [&](int aa, int bb) {
        int a = aa * K_TOP, b = bb * K_TOP;
        unsigned ov[K_TOP];
        int pa = 0, pb = 0;
#pragma unroll
        for (int p = 0; p < K_TOP; ++p) {
            unsigned va = mk[a + pa], vb = mk[b + pb];
            bool ta = (va > vb);
            ov[p] = ta ? va : vb;
            pa += ta ? 1 : 0;
            pb += ta ? 0 : 1;
        }
#pragma unroll
        for (int p = 0; p < K_TOP; ++p) mk[a + p] = ov[p];
    };

    if (tid < 128) merge2(tid, tid + 128);
    __syncthreads();
    if (tid < 64) {
        merge2(tid, tid + 64);
        __builtin_amdgcn_wave_barrier();
        if (tid < 32) merge2(tid, tid + 32);
        __builtin_amdgcn_wave_barrier();
        if (tid < 16) merge2(tid, tid + 16);
        __builtin_amdgcn_wave_barrier();
        if (tid < 8) merge2(tid, tid + 8);
        __builtin_amdgcn_wave_barrier();
        if (tid < 4) merge2(tid, tid + 4);
        __builtin_amdgcn_wave_barrier();
        if (tid < 2) merge2(tid, tid + 2);
        __builtin_amdgcn_wave_barrier();
        if (tid < 1) merge2(0, 1);
        if (tid == 0) {
#pragma unroll
            for (int p = 0; p < K_TOP; ++p)
                topk[row * K_TOP + p] = 4095 - (int)(mk[p] & 0xFFFFu);
        }
    }
}

// ---------------- K3: mutual-NN lists, one row per 1-wave block ----------------

__global__ __launch_bounds__(64) void mutual_kernel(
    const int* __restrict__ topk, int* __restrict__ vnbr, int* __restrict__ vcnt)
{
    int i = blockIdx.x;
    int lane = threadIdx.x;
    int j = -1;
    bool flag = false;
    if (lane < K_TOP) {
        j = topk[i * K_TOP + lane];
#pragma unroll
        for (int b = 0; b < K_TOP; ++b) flag |= (topk[j * K_TOP + b] == i);
    }
    unsigned long long mask = __ballot(flag);
    int cnt = __popcll(mask & 0x3FFull);
    if (flag) {
        int pos = __popcll(mask & ((1ull << lane) - 1ull));
        vnbr[i * K_TOP + pos] = j;
    }
    if (lane >= cnt && lane < K_TOP) vnbr[i * K_TOP + lane] = -1;
    if (lane == 0) vcnt[i] = cnt;
}

// ---------------- K4: W_C_tilda values, one row per 1-wave block ----------------

__global__ __launch_bounds__(64) void wct_kernel(
    const int* __restrict__ vnbr, const int* __restrict__ vcnt, float* __restrict__ wct)
{
    int i = blockIdx.x;
    int lane = threadIdx.x;
    __shared__ int mine[K_TOP];
    int cnt = vcnt[i];
    if (lane < K_TOP) mine[lane] = vnbr[i * K_TOP + lane];
    __syncthreads();
    if (lane < K_TOP) {
        float val = 0.0f;
        if (lane < cnt) {
            int j = mine[lane];
            int cj = vcnt[j];
            int co = 0;
            for (int b = 0; b < cj; ++b) {
                int v = vnbr[j * K_TOP + b];
#pragma unroll
                for (int c = 0; c < K_TOP; ++c)
                    co += (c < cnt && mine[c] == v) ? 1 : 0;
            }
            val = (float)co / fmaxf((float)cnt, 1.0f);
        }
        wct[i * K_TOP + lane] = val;
    }
}

// ---------------- K5: sparse W_C correction, one row per 1-wave block ----------------

__global__ __launch_bounds__(64) void corr_kernel(
    const int* __restrict__ topk, const int* __restrict__ vnbr, const int* __restrict__ vcnt,
    const float* __restrict__ wct, const unsigned short* __restrict__ Sb,
    const float* __restrict__ invm, double* __restrict__ pCorr)
{
    int r = blockIdx.x;
    int lane = threadIdx.x;
    double acc = 0.0;
    if (lane < K_HALF * K_TOP) {
        int a = lane / K_TOP, b = lane % K_TOP;
        int k = topk[r * K_TOP + a];
        if (b < vcnt[k]) {
            int c = vnbr[k * K_TOP + b];
            if (c != r) {
                float w = wct[k * K_TOP + b];
                float sr = bf2f(Sb[(size_t)r * NN + c]);
                float im_r = invm[r];
                float s1 = sr * im_r;
                float r1 = fmaxf(1.0f - s1, 0.0f);
                float g1 = s1 * s1 - r1 * r1;
                float s2 = sr * invm[c];
                float r2 = fmaxf(1.0f - s2, 0.0f);
                float g2 = s2 * s2 - r2 * r2;
                acc = (double)(w * (g1 + g2)) * (1.0 / 20.0);
            }
        }
    }
#pragma unroll
    for (int off = 32; off > 0; off >>= 1) acc += __shfl_down(acc, off);
    if (lane == 0) pCorr[r] = acc;
}

// ---------------- K6: final reduce ----------------

__global__ __launch_bounds__(256) void final_kernel(
    const double* __restrict__ pDense, const double* __restrict__ pCorr, float* __restrict__ out)
{
    int tid = threadIdx.x;
    double a = 0.0;
    for (int j = tid; j < NN; j += 256) a += pDense[j] + pCorr[j];
    __shared__ double red[256];
    double total = block_reduce_sum_d(a, red);
    if (tid == 0) out[0] = (float)(total / ((double)NN * (double)(NN - 1)));
}

// ---------------- launcher ----------------

extern "C" void kernel_launch(void* const* d_in, const int* in_sizes, int n_in,
                              void* d_out, int out_size, void* d_ws, size_t ws_size,
                              hipStream_t stream)
{
    const float* s = (const float*)d_in[0];
    const float* t = (const float*)d_in[1];
    const int* idx = (const int*)d_in[2];
    float* out = (float*)d_out;

    char* base = (char*)d_ws;
    size_t off = 0;
    auto alloc = [&](size_t bytes) -> void* {
        void* p = base + off;
        off = (off + bytes + 511) & ~(size_t)511;
        return p;
    };

    unsigned short* Sb = (unsigned short*)alloc((size_t)NN * NN * 2);
    unsigned short* Wb = (unsigned short*)alloc((size_t)NN * NN * 2);
    unsigned short* shi = (unsigned short*)alloc((size_t)NN * DD * 2);
    unsigned short* thi = (unsigned short*)alloc((size_t)NN * DD * 2);
    float* sn2  = (float*)alloc(NN * 4);
    float* tn2  = (float*)alloc(NN * 4);
    float* invm = (float*)alloc(NN * 4);
    int* topk   = (int*)alloc(NN * K_TOP * 4);
    int* vnbr   = (int*)alloc(NN * K_TOP * 4);
    int* vcnt   = (int*)alloc(NN * 4);
    float* wct  = (float*)alloc(NN * K_TOP * 4);
    double* pDense = (double*)alloc(NN * 8);
    double* pCorr  = (double*)alloc(NN * 8);
    (void)ws_size;

    int ntile = NN / BM;
    int ntri = ntile * (ntile + 1) / 2;

    prep_kernel<<<NN, 256, 0, stream>>>(s, t, shi, thi, sn2, tn2);
    gram_fused_kernel<<<2 * ntri, 256, 0, stream>>>(shi, thi, sn2, tn2, Sb, Wb, ntri);
    fused_row_kernel<<<NN, 256, 0, stream>>>(Sb, Wb, idx, invm, topk, pDense);
    mutual_kernel<<<NN, 64, 0, stream>>>(topk, vnbr, vcnt);
    wct_kernel<<<NN, 64, 0, stream>>>(vnbr, vcnt, wct);
    corr_kernel<<<NN, 64, 0, stream>>>(topk, vnbr, vcnt, wct, Sb, invm, pCorr);
    final_kernel<<<1, 256, 0, stream>>>(pDense, pCorr, out);
}